// Round 8
// baseline (381.612 us; speedup 1.0000x reference)
//
#include <hip/hip_runtime.h>

// GNN: 2 x (SimpleConv(mean, cat) -> Linear(256->128) -> ReLU)
// N=50000 nodes, E=640000 edges, H=128.
//
// R1: k_agg latency-bound -> packed (src,att) CSR + LDS stage + x4 unroll.
// R2: k_scan single-block 90us -> multi-block scan.
// R3: bf16 hidden pipeline + LDS-free MFMA bf16 GEMM (fp32 accum).
// R4: k_agg one-wave-per-node ushort2 gathers; A = [X | AGG] two-buffer GEMM.
// R5: launch-count reduction (worth ~8.6us/launch).
// R6: k_layer fusion REGRESSED (serial per-wave gather) -> reverted.
// R7: padded CSR (cap=48), 6 launches. k_fill = 43us, write-amp bound
//     (WRITE 40.6MB for 5.1MB logical: random 8B scatters dirty 64B lines).
// R8: two-pass binned fill: pass1 appends to 782 coarse buckets (dense,
//     time-ordered appends -> ~1x line amp); pass2 builds padded CSR in LDS
//     per bucket, writes fully coalesced.

#define HDIM 128
#define CAP 48            // padded CSR slots/node; P(deg>48 | Poisson 12.8) ~ 3e-14
#define BSH 6             // bucket = dst >> 6  (64 nodes per bucket)
#define BNODES 64
#define BCAP 1280         // bucket capacity; avg 818, +16 sigma
#define NOVF_CAP (640000 / 4)

typedef __bf16 bf16x8 __attribute__((ext_vector_type(8)));
typedef float floatx4 __attribute__((ext_vector_type(4)));

__device__ __forceinline__ unsigned short f2bf(float f) {
    unsigned int u = __float_as_uint(f);
    unsigned int r = (u + 0x7fff + ((u >> 16) & 1)) >> 16;   // RNE
    return (unsigned short)r;
}
__device__ __forceinline__ float bf2f(unsigned short b) {
    return __uint_as_float((unsigned int)b << 16);
}

// ---- fused setup: zero bucket counters | cast data->bf16 | prepW1 | prepW2 ----
__global__ __launch_bounds__(256) void k_setup(int* __restrict__ bcnt, int nz,
                                               const float* __restrict__ data,
                                               unsigned short* __restrict__ data_bf, int n4,
                                               const float* __restrict__ w1,
                                               unsigned short* __restrict__ w1t,
                                               const float* __restrict__ w2,
                                               unsigned short* __restrict__ w2t,
                                               int zb, int cb) {
    int b = blockIdx.x;
    int t = threadIdx.x;
    if (b < zb) {
        int i = b * 256 + t;
        if (i < nz) bcnt[i] = 0;
        return;
    }
    b -= zb;
    if (b < cb) {
        int i = b * 256 + t;
        if (i < n4) {
            float4 v = ((const float4*)data)[i];
            ushort4 o;
            o.x = f2bf(v.x); o.y = f2bf(v.y); o.z = f2bf(v.z); o.w = f2bf(v.w);
            ((ushort4*)data_bf)[i] = o;
        }
        return;
    }
    b -= cb;
    {
        const float* w = (b < 128) ? w1 : w2;
        unsigned short* wt = (b < 128) ? w1t : w2t;
        int bb = (b < 128) ? b : b - 128;
        int idx = bb * 256 + t;          // 0..32767
        int k = idx >> 7;                // 0..255
        int n = idx & 127;               // 0..127
        wt[(size_t)n * 256 + k] = f2bf(w[(size_t)k * 128 + n]);
    }
}

// Pass 1: bin edges by dst>>BSH. Record = { (src<<BSH)|dst_local , att } (8B).
// Appends to a bucket are time-sequential -> dense line utilization.
// Bucket overflow (>= BCAP) -> bovf list {dst, src, att} (consumed in pass 2).
__global__ __launch_bounds__(256) void k_bin(const int* __restrict__ edge, int E,
                                             const float* __restrict__ att,
                                             int* __restrict__ bcnt,
                                             float2* __restrict__ brec,
                                             int* __restrict__ bovf_cnt,
                                             float4* __restrict__ bovf) {
    __shared__ int s_or;
    int t = threadIdx.x;
    if (t == 0) s_or = 0;
    __syncthreads();
    int nw = 2 * E < 512 ? 2 * E : 512;
    int iw = t * 2 + 1;
    int vw = (iw < nw) ? edge[iw] : 0;
    if (vw != 0) atomicOr(&s_or, 1);
    __syncthreads();
    int sh = (s_or == 0) ? 1 : 0;  // 1 => int64 stride, 0 => int32

    int e = blockIdx.x * 256 + t;
    if (e < E) {
        int s = edge[(size_t)e << sh];
        int d = edge[(size_t)(E + e) << sh];
        float a = att[e];
        int b = d >> BSH;
        int pos = atomicAdd(&bcnt[b], 1);
        if (pos < BCAP) {
            unsigned int u = ((unsigned int)s << BSH) | (unsigned int)(d & (BNODES - 1));
            brec[(size_t)b * BCAP + pos] = make_float2(__int_as_float((int)u), a);
        } else {
            int oi = atomicAdd(bovf_cnt, 1);   // <= E total, capacity exact
            bovf[oi] = make_float4(__int_as_float(d), __int_as_float(s), a, 0.f);
        }
    }
}

// Pass 2: one block per bucket. Build padded-CSR image for 64 nodes in LDS
// (LDS atomics), inject pass-1 overflow, write image + cursors coalesced.
// Node-slot overflow (>= CAP) -> novf list (drained in k_agg).
__global__ __launch_bounds__(256) void k_binfill(const float2* __restrict__ brec,
                                                 const int* __restrict__ bcnt,
                                                 const float4* __restrict__ bovf,
                                                 const int* __restrict__ bovf_cnt,
                                                 float2* __restrict__ pse,
                                                 int* __restrict__ cursor,
                                                 int* __restrict__ novf_cnt,
                                                 float4* __restrict__ novf, int N) {
    __shared__ float2 img[BNODES][CAP];
    __shared__ int lcur[BNODES];
    int t = threadIdx.x;
    int b = blockIdx.x;
    if (t < BNODES) lcur[t] = 0;
    __syncthreads();

    int cnt = min(bcnt[b], BCAP);
    const float2* rec = brec + (size_t)b * BCAP;
    for (int i = t; i < cnt; i += 256) {
        float2 r = rec[i];
        unsigned int u = (unsigned int)__float_as_int(r.x);
        int dl = (int)(u & (BNODES - 1));
        int src = (int)(u >> BSH);
        int slot = atomicAdd(&lcur[dl], 1);
        if (slot < CAP) {
            img[dl][slot] = make_float2(__int_as_float(src), r.y);
        } else {
            int oi = atomicAdd(novf_cnt, 1);
            if (oi < NOVF_CAP)
                novf[oi] = make_float4(__int_as_float(b * BNODES + dl),
                                       __int_as_float(src), r.y, 0.f);
        }
    }
    int oc = bovf_cnt[0];
    for (int i = t; i < oc; i += 256) {
        float4 f = bovf[i];
        int d = __float_as_int(f.x);
        if ((d >> BSH) == b) {
            int dl = d & (BNODES - 1);
            int slot = atomicAdd(&lcur[dl], 1);
            if (slot < CAP) {
                img[dl][slot] = make_float2(f.y, f.z);
            } else {
                int oi = atomicAdd(novf_cnt, 1);
                if (oi < NOVF_CAP) novf[oi] = make_float4(f.x, f.y, f.z, 0.f);
            }
        }
    }
    __syncthreads();

    // Coalesced write-out of the padded image (dead slots harmless).
    size_t base = (size_t)b * BNODES * CAP;
    size_t lim = (size_t)N * CAP;
    const float2* imgf = &img[0][0];
    for (int i = t; i < BNODES * CAP; i += 256) {
        size_t g = base + i;
        if (g < lim) pse[g] = imgf[i];
    }
    if (t < BNODES) {
        int n = b * BNODES + t;
        if (n < N) cursor[n] = lcur[t];
    }
}

// One WAVE per node, 2 nodes per 128-thread block. Lane covers 2 columns via
// ushort2 gathers. Single LDS stage covers all slots (deg <= CAP = 48).
__global__ __launch_bounds__(128) void k_agg(const unsigned short* __restrict__ x,
                                             const float2* __restrict__ pse,
                                             const int* __restrict__ cursor,
                                             const int* __restrict__ ovf_cnt,
                                             const float4* __restrict__ ovf,
                                             unsigned short* __restrict__ agg, int N) {
    int wave = threadIdx.x >> 6;
    int lane = threadIdx.x & 63;
    int n = blockIdx.x * 2 + wave;
    bool valid = n < N;
    int deg = valid ? cursor[n] : 0;
    int m = min(deg, CAP);

    __shared__ float2 sp[2][CAP];
    if (lane < m) sp[wave][lane] = pse[(size_t)n * CAP + lane];
    __syncthreads();

    float sx = 0.f, sy = 0.f;
    int j = 0;
    for (; j + 4 <= m; j += 4) {
        float2 p0 = sp[wave][j + 0];
        float2 p1 = sp[wave][j + 1];
        float2 p2 = sp[wave][j + 2];
        float2 p3 = sp[wave][j + 3];
        unsigned int u0 = *(const unsigned int*)(x + (size_t)__float_as_int(p0.x) * HDIM + 2 * lane);
        unsigned int u1 = *(const unsigned int*)(x + (size_t)__float_as_int(p1.x) * HDIM + 2 * lane);
        unsigned int u2 = *(const unsigned int*)(x + (size_t)__float_as_int(p2.x) * HDIM + 2 * lane);
        unsigned int u3 = *(const unsigned int*)(x + (size_t)__float_as_int(p3.x) * HDIM + 2 * lane);
        sx = fmaf(bf2f((unsigned short)(u0 & 0xffff)), p0.y, sx);
        sy = fmaf(bf2f((unsigned short)(u0 >> 16)), p0.y, sy);
        sx = fmaf(bf2f((unsigned short)(u1 & 0xffff)), p1.y, sx);
        sy = fmaf(bf2f((unsigned short)(u1 >> 16)), p1.y, sy);
        sx = fmaf(bf2f((unsigned short)(u2 & 0xffff)), p2.y, sx);
        sy = fmaf(bf2f((unsigned short)(u2 >> 16)), p2.y, sy);
        sx = fmaf(bf2f((unsigned short)(u3 & 0xffff)), p3.y, sx);
        sy = fmaf(bf2f((unsigned short)(u3 >> 16)), p3.y, sy);
    }
    for (; j < m; ++j) {
        float2 p = sp[wave][j];
        unsigned int u = *(const unsigned int*)(x + (size_t)__float_as_int(p.x) * HDIM + 2 * lane);
        sx = fmaf(bf2f((unsigned short)(u & 0xffff)), p.y, sx);
        sy = fmaf(bf2f((unsigned short)(u >> 16)), p.y, sy);
    }

    // Node-slot overflow correctness path (normally empty).
    int oc = min(ovf_cnt[0], NOVF_CAP);
    if (oc > 0 && valid) {
        for (int k = 0; k < oc; ++k) {
            float4 f = ovf[k];
            if (__float_as_int(f.x) == n) {
                unsigned int u = *(const unsigned int*)(x + (size_t)__float_as_int(f.y) * HDIM + 2 * lane);
                sx = fmaf(bf2f((unsigned short)(u & 0xffff)), f.z, sx);
                sy = fmaf(bf2f((unsigned short)(u >> 16)), f.z, sy);
            }
        }
    }

    if (valid) {
        float md = fmaxf((float)deg, 1.0f);
        unsigned int o = (unsigned int)f2bf(sx / md) | ((unsigned int)f2bf(sy / md) << 16);
        *(unsigned int*)(agg + (size_t)n * HDIM + 2 * lane) = o;
    }
}

// out[M,128] = relu( [X | AGG][M,256]bf16 @ W[256,128] + b ), MFMA 16x16x32.
// LDS-free: A-frags from X (k<128) / AGG (k>=128); B-frags from Wt[128,256].
// C/D: col=lane&15, row=quad*4+reg. Block = 4 waves, 64 rows/block.
__global__ __launch_bounds__(256) void k_gemm_mfma(const unsigned short* __restrict__ X,
                                                   const unsigned short* __restrict__ AGG,
                                                   const unsigned short* __restrict__ Wt,
                                                   const float* __restrict__ bias,
                                                   float* __restrict__ outF,
                                                   unsigned short* __restrict__ outB,
                                                   int M) {
    int tid = threadIdx.x;
    int wave = tid >> 6;
    int lane = tid & 63;
    int l16 = lane & 15;
    int quad = lane >> 4;

    int row = blockIdx.x * 64 + wave * 16 + l16;
    int rowA = min(row, M - 1);
    const unsigned short* xrow = X + (size_t)rowA * HDIM + quad * 8;
    const unsigned short* arow = AGG + (size_t)rowA * HDIM + quad * 8;

    floatx4 acc[8];
#pragma unroll
    for (int c = 0; c < 8; ++c) acc[c] = (floatx4){0.f, 0.f, 0.f, 0.f};

#pragma unroll
    for (int kc = 0; kc < 8; ++kc) {
        bf16x8 af = (kc < 4) ? *(const bf16x8*)(xrow + kc * 32)
                             : *(const bf16x8*)(arow + (kc - 4) * 32);
#pragma unroll
        for (int c = 0; c < 8; ++c) {
            const unsigned short* bptr = Wt + (size_t)(c * 16 + l16) * 256 + kc * 32 + quad * 8;
            bf16x8 bfr = *(const bf16x8*)bptr;
            acc[c] = __builtin_amdgcn_mfma_f32_16x16x32_bf16(af, bfr, acc[c], 0, 0, 0);
        }
    }

    int orow0 = blockIdx.x * 64 + wave * 16 + quad * 4;
#pragma unroll
    for (int c = 0; c < 8; ++c) {
        int col = c * 16 + l16;
        float bv = bias[col];
#pragma unroll
        for (int r = 0; r < 4; ++r) {
            int orow = orow0 + r;
            if (orow < M) {
                float v = fmaxf(acc[c][r] + bv, 0.f);
                if (outF) outF[(size_t)orow * 128 + col] = v;
                else outB[(size_t)orow * 128 + col] = f2bf(v);
            }
        }
    }
}

extern "C" void kernel_launch(void* const* d_in, const int* in_sizes, int n_in,
                              void* d_out, int out_size, void* d_ws, size_t ws_size,
                              hipStream_t stream) {
    const float* data = (const float*)d_in[0];
    const int* edge = (const int*)d_in[1];
    const float* att = (const float*)d_in[2];
    const float* w1 = (const float*)d_in[3];
    const float* b1 = (const float*)d_in[4];
    const float* w2 = (const float*)d_in[5];
    const float* b2 = (const float*)d_in[6];

    const int N = in_sizes[0] / HDIM;
    const int E = in_sizes[1] / 2;
    const int NB = (N + BNODES - 1) / BNODES;   // 782 buckets

    char* ws = (char*)d_ws;
    size_t o = 0;
    auto carve = [&](size_t bytes) -> char* {
        char* r = ws + o;
        o = (o + bytes + 255) & ~(size_t)255;
        return r;
    };
    int* bcnt = (int*)carve((size_t)(NB + 8) * 4);   // bcnt[NB] + bovf_cnt + novf_cnt
    int* bovf_cnt = bcnt + NB;
    int* novf_cnt = bcnt + NB + 1;
    int* cursor = (int*)carve((size_t)N * 4);
    float2* brec = (float2*)carve((size_t)NB * BCAP * 8);   // 8.0 MB
    float4* bovf = (float4*)carve((size_t)E * 16);          // exact worst case
    float4* novf = (float4*)carve((size_t)NOVF_CAP * 16);   // clamped
    float2* pse = (float2*)carve((size_t)N * CAP * 8);      // padded CSR {src, att}
    unsigned short* data_bf = (unsigned short*)carve((size_t)N * 128 * 2);
    unsigned short* w1t = (unsigned short*)carve(256 * 128 * 2);
    unsigned short* w2t = (unsigned short*)carve(256 * 128 * 2);
    unsigned short* agg_bf = (unsigned short*)carve((size_t)N * 128 * 2);
    unsigned short* out1_bf = (unsigned short*)carve((size_t)N * 128 * 2);
    float* outF = (float*)d_out;

    int nz = NB + 8;
    int zb = (nz + 255) / 256;
    int n4 = N * 128 / 4;
    int cb = (n4 + 255) / 256;
    k_setup<<<zb + cb + 256, 256, 0, stream>>>(bcnt, nz, data, data_bf, n4,
                                               w1, w1t, w2, w2t, zb, cb);

    k_bin<<<(E + 255) / 256, 256, 0, stream>>>(edge, E, att, bcnt, brec, bovf_cnt, bovf);
    k_binfill<<<NB, 256, 0, stream>>>(brec, bcnt, bovf, bovf_cnt, pse, cursor,
                                      novf_cnt, novf, N);

    int ga = (N + 1) / 2;
    int gb = (N + 63) / 64;
    // Layer 1
    k_agg<<<ga, 128, 0, stream>>>(data_bf, pse, cursor, novf_cnt, novf, agg_bf, N);
    k_gemm_mfma<<<gb, 256, 0, stream>>>(data_bf, agg_bf, w1t, b1, nullptr, out1_bf, N);
    // Layer 2
    k_agg<<<ga, 128, 0, stream>>>(out1_bf, pse, cursor, novf_cnt, novf, agg_bf, N);
    k_gemm_mfma<<<gb, 256, 0, stream>>>(out1_bf, agg_bf, w2t, b2, outF, nullptr, N);
}

// Round 9
// 255.863 us; speedup vs baseline: 1.4915x; 1.4915x over previous
//
#include <hip/hip_runtime.h>

// GNN: 2 x (SimpleConv(mean, cat) -> Linear(256->128) -> ReLU)
// N=50000 nodes, E=640000 edges, H=128.
//
// R1: k_agg latency-bound -> packed (src,att) CSR + LDS stage + x4 unroll.
// R2: k_scan single-block 90us -> multi-block scan.
// R3: bf16 hidden pipeline + LDS-free MFMA bf16 GEMM (fp32 accum).
// R4: k_agg one-wave-per-node ushort2 gathers; A = [X | AGG] two-buffer GEMM.
// R5: launch-count reduction (worth ~8.6us/launch).
// R6: k_layer fusion REGRESSED (serial per-wave gather) -> reverted.
// R7: padded CSR (cap=48), 6 launches, 258us. k_fill=43us write-amp bound.
// R8: binned fill REGRESSED (k_bin 154us: 782 counters -> ~50 cache lines,
//     ~12.8k serialized atomic RMWs/line). Scatter-fill stays. Reverted.
// R9: k_agg half-wave pairing: lane covers 4 cols (8B), half-waves take
//     even/odd edges -> one dwordx2 instr fetches TWO src rows (512B);
//     x4 unroll = 8 rows in flight; __shfl_xor(32) combine.

#define HDIM 128
#define CAP 48            // padded CSR slots/node; P(deg>48 | Poisson 12.8) ~ 3e-14

typedef __bf16 bf16x8 __attribute__((ext_vector_type(8)));
typedef float floatx4 __attribute__((ext_vector_type(4)));

__device__ __forceinline__ unsigned short f2bf(float f) {
    unsigned int u = __float_as_uint(f);
    unsigned int r = (u + 0x7fff + ((u >> 16) & 1)) >> 16;   // RNE
    return (unsigned short)r;
}
__device__ __forceinline__ float bf2f(unsigned short b) {
    return __uint_as_float((unsigned int)b << 16);
}

// ---- fused setup: zero cursor/ovf | cast data->bf16 | prepW1 | prepW2 ----
__global__ __launch_bounds__(256) void k_setup(int* __restrict__ cursor, int nz,
                                               const float* __restrict__ data,
                                               unsigned short* __restrict__ data_bf, int n4,
                                               const float* __restrict__ w1,
                                               unsigned short* __restrict__ w1t,
                                               const float* __restrict__ w2,
                                               unsigned short* __restrict__ w2t,
                                               int zb, int cb) {
    int b = blockIdx.x;
    int t = threadIdx.x;
    if (b < zb) {
        int i = b * 256 + t;
        if (i < nz) cursor[i] = 0;
        return;
    }
    b -= zb;
    if (b < cb) {
        int i = b * 256 + t;
        if (i < n4) {
            float4 v = ((const float4*)data)[i];
            ushort4 o;
            o.x = f2bf(v.x); o.y = f2bf(v.y); o.z = f2bf(v.z); o.w = f2bf(v.w);
            ((ushort4*)data_bf)[i] = o;
        }
        return;
    }
    b -= cb;
    {
        const float* w = (b < 128) ? w1 : w2;
        unsigned short* wt = (b < 128) ? w1t : w2t;
        int bb = (b < 128) ? b : b - 128;
        int idx = bb * 256 + t;          // 0..32767
        int k = idx >> 7;                // 0..255
        int n = idx & 127;               // 0..127
        wt[(size_t)n * 256 + k] = f2bf(w[(size_t)k * 128 + n]);
    }
}

// Padded-CSR fill: slot = atomicAdd(cursor[dst]); pse[dst*CAP+slot] = {src,att}.
// Per-block redundant int64/int32 detect (odd words all-zero => int64).
// Overflow (slot >= CAP): append {dst,src,att} to ovf list (correctness path).
__global__ __launch_bounds__(256) void k_fill(const int* __restrict__ edge, int E,
                                              const float* __restrict__ att,
                                              int* __restrict__ cursor,
                                              int* __restrict__ ovf_cnt,
                                              float2* __restrict__ pse,
                                              float4* __restrict__ ovf) {
    __shared__ int s_or;
    int t = threadIdx.x;
    if (t == 0) s_or = 0;
    __syncthreads();
    int nw = 2 * E < 512 ? 2 * E : 512;
    int iw = t * 2 + 1;
    int vw = (iw < nw) ? edge[iw] : 0;
    if (vw != 0) atomicOr(&s_or, 1);
    __syncthreads();
    int sh = (s_or == 0) ? 1 : 0;  // 1 => int64 stride, 0 => int32

    int e = blockIdx.x * 256 + t;
    if (e < E) {
        int s = edge[(size_t)e << sh];
        int d = edge[(size_t)(E + e) << sh];
        int slot = atomicAdd(&cursor[d], 1);
        float a = att[e];
        if (slot < CAP) {
            pse[(size_t)d * CAP + slot] = make_float2(__int_as_float(s), a);
        } else {
            int oi = atomicAdd(ovf_cnt, 1);
            ovf[oi] = make_float4(__int_as_float(d), __int_as_float(s), a, 0.f);
        }
    }
}

// One WAVE per node, 2 nodes per 128-thread block. Lane covers 4 cols (8B);
// half-wave 0 takes even edges, half-wave 1 odd edges -> one dwordx2 instr
// gathers two full 256B src rows. x4 unroll = 8 rows in flight.
// Final cross-half combine via __shfl_xor(.,32).
__global__ __launch_bounds__(128) void k_agg(const unsigned short* __restrict__ x,
                                             const float2* __restrict__ pse,
                                             const int* __restrict__ cursor,
                                             const int* __restrict__ ovf_cnt,
                                             const float4* __restrict__ ovf,
                                             unsigned short* __restrict__ agg, int N) {
    int wave = threadIdx.x >> 6;
    int lane = threadIdx.x & 63;
    int half = lane >> 5;        // which edge of a pair
    int l32 = lane & 31;         // col group: cols 4*l32 .. 4*l32+3
    int n = blockIdx.x * 2 + wave;
    bool valid = n < N;
    int deg = valid ? cursor[n] : 0;
    int m = min(deg, CAP);

    __shared__ float2 sp[2][CAP];
    if (lane < m) sp[wave][lane] = pse[(size_t)n * CAP + lane];
    __syncthreads();

    const unsigned short* xb = x + 4 * l32;
    float s0 = 0.f, s1 = 0.f, s2 = 0.f, s3 = 0.f;

#define ACC(u, a)                                                   \
    do {                                                            \
        s0 = fmaf(bf2f((unsigned short)((u).x & 0xffff)), (a), s0); \
        s1 = fmaf(bf2f((unsigned short)((u).x >> 16)), (a), s1);    \
        s2 = fmaf(bf2f((unsigned short)((u).y & 0xffff)), (a), s2); \
        s3 = fmaf(bf2f((unsigned short)((u).y >> 16)), (a), s3);    \
    } while (0)

    int j = 0;
    for (; j + 8 <= m; j += 8) {
        float2 pA = sp[wave][j + 0 + half];
        float2 pB = sp[wave][j + 2 + half];
        float2 pC = sp[wave][j + 4 + half];
        float2 pD = sp[wave][j + 6 + half];
        uint2 uA = *(const uint2*)(xb + (size_t)__float_as_int(pA.x) * HDIM);
        uint2 uB = *(const uint2*)(xb + (size_t)__float_as_int(pB.x) * HDIM);
        uint2 uC = *(const uint2*)(xb + (size_t)__float_as_int(pC.x) * HDIM);
        uint2 uD = *(const uint2*)(xb + (size_t)__float_as_int(pD.x) * HDIM);
        ACC(uA, pA.y);
        ACC(uB, pB.y);
        ACC(uC, pC.y);
        ACC(uD, pD.y);
    }
    for (; j + 2 <= m; j += 2) {
        float2 p = sp[wave][j + half];
        uint2 u = *(const uint2*)(xb + (size_t)__float_as_int(p.x) * HDIM);
        ACC(u, p.y);
    }
    if (j < m && half == 0) {   // single leftover edge
        float2 p = sp[wave][j];
        uint2 u = *(const uint2*)(xb + (size_t)__float_as_int(p.x) * HDIM);
        ACC(u, p.y);
    }

    // Overflow correctness path (normally ovf_cnt == 0 -> skipped).
    int oc = ovf_cnt[0];
    if (oc > 0 && valid) {
        for (int k = half; k < oc; k += 2) {
            float4 f = ovf[k];
            if (__float_as_int(f.x) == n) {
                uint2 u = *(const uint2*)(xb + (size_t)__float_as_int(f.y) * HDIM);
                ACC(u, f.z);
            }
        }
    }
#undef ACC

    s0 += __shfl_xor(s0, 32);
    s1 += __shfl_xor(s1, 32);
    s2 += __shfl_xor(s2, 32);
    s3 += __shfl_xor(s3, 32);

    if (valid && half == 0) {
        float md = fmaxf((float)deg, 1.0f);
        ushort4 o;
        o.x = f2bf(s0 / md);
        o.y = f2bf(s1 / md);
        o.z = f2bf(s2 / md);
        o.w = f2bf(s3 / md);
        *(ushort4*)(agg + (size_t)n * HDIM + 4 * l32) = o;
    }
}

// out[M,128] = relu( [X | AGG][M,256]bf16 @ W[256,128] + b ), MFMA 16x16x32.
// LDS-free: A-frags from X (k<128) / AGG (k>=128); B-frags from Wt[128,256].
// C/D: col=lane&15, row=quad*4+reg. Block = 4 waves, 64 rows/block.
__global__ __launch_bounds__(256) void k_gemm_mfma(const unsigned short* __restrict__ X,
                                                   const unsigned short* __restrict__ AGG,
                                                   const unsigned short* __restrict__ Wt,
                                                   const float* __restrict__ bias,
                                                   float* __restrict__ outF,
                                                   unsigned short* __restrict__ outB,
                                                   int M) {
    int tid = threadIdx.x;
    int wave = tid >> 6;
    int lane = tid & 63;
    int l16 = lane & 15;
    int quad = lane >> 4;

    int row = blockIdx.x * 64 + wave * 16 + l16;
    int rowA = min(row, M - 1);
    const unsigned short* xrow = X + (size_t)rowA * HDIM + quad * 8;
    const unsigned short* arow = AGG + (size_t)rowA * HDIM + quad * 8;

    floatx4 acc[8];
#pragma unroll
    for (int c = 0; c < 8; ++c) acc[c] = (floatx4){0.f, 0.f, 0.f, 0.f};

#pragma unroll
    for (int kc = 0; kc < 8; ++kc) {
        bf16x8 af = (kc < 4) ? *(const bf16x8*)(xrow + kc * 32)
                             : *(const bf16x8*)(arow + (kc - 4) * 32);
#pragma unroll
        for (int c = 0; c < 8; ++c) {
            const unsigned short* bptr = Wt + (size_t)(c * 16 + l16) * 256 + kc * 32 + quad * 8;
            bf16x8 bfr = *(const bf16x8*)bptr;
            acc[c] = __builtin_amdgcn_mfma_f32_16x16x32_bf16(af, bfr, acc[c], 0, 0, 0);
        }
    }

    int orow0 = blockIdx.x * 64 + wave * 16 + quad * 4;
#pragma unroll
    for (int c = 0; c < 8; ++c) {
        int col = c * 16 + l16;
        float bv = bias[col];
#pragma unroll
        for (int r = 0; r < 4; ++r) {
            int orow = orow0 + r;
            if (orow < M) {
                float v = fmaxf(acc[c][r] + bv, 0.f);
                if (outF) outF[(size_t)orow * 128 + col] = v;
                else outB[(size_t)orow * 128 + col] = f2bf(v);
            }
        }
    }
}

extern "C" void kernel_launch(void* const* d_in, const int* in_sizes, int n_in,
                              void* d_out, int out_size, void* d_ws, size_t ws_size,
                              hipStream_t stream) {
    const float* data = (const float*)d_in[0];
    const int* edge = (const int*)d_in[1];
    const float* att = (const float*)d_in[2];
    const float* w1 = (const float*)d_in[3];
    const float* b1 = (const float*)d_in[4];
    const float* w2 = (const float*)d_in[5];
    const float* b2 = (const float*)d_in[6];

    const int N = in_sizes[0] / HDIM;
    const int E = in_sizes[1] / 2;

    char* ws = (char*)d_ws;
    size_t o = 0;
    auto carve = [&](size_t bytes) -> char* {
        char* r = ws + o;
        o = (o + bytes + 255) & ~(size_t)255;
        return r;
    };
    int* cursor = (int*)carve((size_t)(N + 4) * 4);   // cursor[N] + ovf_cnt at [N]
    int* ovf_cnt = cursor + N;
    float2* pse = (float2*)carve((size_t)N * CAP * 8);        // padded CSR {src, att}
    float4* ovf = (float4*)carve((size_t)E * 16);             // overflow (usually empty)
    unsigned short* data_bf = (unsigned short*)carve((size_t)N * 128 * 2);
    unsigned short* w1t = (unsigned short*)carve(256 * 128 * 2);
    unsigned short* w2t = (unsigned short*)carve(256 * 128 * 2);
    unsigned short* agg_bf = (unsigned short*)carve((size_t)N * 128 * 2);
    unsigned short* out1_bf = (unsigned short*)carve((size_t)N * 128 * 2);
    float* outF = (float*)d_out;

    int nz = N + 4;
    int zb = (nz + 255) / 256;
    int n4 = N * 128 / 4;
    int cb = (n4 + 255) / 256;
    k_setup<<<zb + cb + 256, 256, 0, stream>>>(cursor, nz, data, data_bf, n4,
                                               w1, w1t, w2, w2t, zb, cb);

    k_fill<<<(E + 255) / 256, 256, 0, stream>>>(edge, E, att, cursor, ovf_cnt, pse, ovf);

    int ga = (N + 1) / 2;
    int gb = (N + 63) / 64;
    // Layer 1
    k_agg<<<ga, 128, 0, stream>>>(data_bf, pse, cursor, ovf_cnt, ovf, agg_bf, N);
    k_gemm_mfma<<<gb, 256, 0, stream>>>(data_bf, agg_bf, w1t, b1, nullptr, out1_bf, N);
    // Layer 2
    k_agg<<<ga, 128, 0, stream>>>(out1_bf, pse, cursor, ovf_cnt, ovf, agg_bf, N);
    k_gemm_mfma<<<gb, 256, 0, stream>>>(out1_bf, agg_bf, w2t, b2, outF, nullptr, N);
}

// Round 10
// 216.895 us; speedup vs baseline: 1.7594x; 1.1797x over previous
//
#include <hip/hip_runtime.h>

// GNN: 2 x (SimpleConv(mean, cat) -> Linear(256->128) -> ReLU)
// N=50000 nodes, E=640000 edges, H=128.
//
// R1: k_agg latency-bound -> packed (src,att) CSR + LDS stage + x4 unroll.
// R2: k_scan single-block 90us -> multi-block scan.
// R3: bf16 hidden pipeline + LDS-free MFMA bf16 GEMM (fp32 accum).
// R4: k_agg one-wave-per-node ushort2 gathers; A = [X | AGG] two-buffer GEMM.
// R5: launch-count reduction (worth ~8.6us/launch).
// R6: k_layer fusion REGRESSED (serial per-wave gather) -> reverted.
// R7: padded CSR (cap=48), 6 launches, 258us. k_fill=43us write-amp bound.
// R8: binned fill REGRESSED (atomic line contention on 782 counters). Reverted.
// R9: k_agg half-wave pairing (dwordx2 = 2 rows/instr). 255.9us.
// R10: gemm was latency-bound (43us, MfmaUtil 2.6%, occ 22%: 64 global
//      B-frag loads/wave @ ~200cyc, few in flight). Stage Wt in LDS (64KB,
//      XOR-swizzled, <=4-way conflicts); preload A-frags to regs.

#define HDIM 128
#define CAP 48            // padded CSR slots/node; P(deg>48 | Poisson 12.8) ~ 3e-14

typedef __bf16 bf16x8 __attribute__((ext_vector_type(8)));
typedef float floatx4 __attribute__((ext_vector_type(4)));

__device__ __forceinline__ unsigned short f2bf(float f) {
    unsigned int u = __float_as_uint(f);
    unsigned int r = (u + 0x7fff + ((u >> 16) & 1)) >> 16;   // RNE
    return (unsigned short)r;
}
__device__ __forceinline__ float bf2f(unsigned short b) {
    return __uint_as_float((unsigned int)b << 16);
}

// ---- fused setup: zero cursor/ovf | cast data->bf16 | prepW1 | prepW2 ----
__global__ __launch_bounds__(256) void k_setup(int* __restrict__ cursor, int nz,
                                               const float* __restrict__ data,
                                               unsigned short* __restrict__ data_bf, int n4,
                                               const float* __restrict__ w1,
                                               unsigned short* __restrict__ w1t,
                                               const float* __restrict__ w2,
                                               unsigned short* __restrict__ w2t,
                                               int zb, int cb) {
    int b = blockIdx.x;
    int t = threadIdx.x;
    if (b < zb) {
        int i = b * 256 + t;
        if (i < nz) cursor[i] = 0;
        return;
    }
    b -= zb;
    if (b < cb) {
        int i = b * 256 + t;
        if (i < n4) {
            float4 v = ((const float4*)data)[i];
            ushort4 o;
            o.x = f2bf(v.x); o.y = f2bf(v.y); o.z = f2bf(v.z); o.w = f2bf(v.w);
            ((ushort4*)data_bf)[i] = o;
        }
        return;
    }
    b -= cb;
    {
        const float* w = (b < 128) ? w1 : w2;
        unsigned short* wt = (b < 128) ? w1t : w2t;
        int bb = (b < 128) ? b : b - 128;
        int idx = bb * 256 + t;          // 0..32767
        int k = idx >> 7;                // 0..255
        int n = idx & 127;               // 0..127
        wt[(size_t)n * 256 + k] = f2bf(w[(size_t)k * 128 + n]);
    }
}

// Padded-CSR fill: slot = atomicAdd(cursor[dst]); pse[dst*CAP+slot] = {src,att}.
// Per-block redundant int64/int32 detect (odd words all-zero => int64).
// Overflow (slot >= CAP): append {dst,src,att} to ovf list (correctness path).
__global__ __launch_bounds__(256) void k_fill(const int* __restrict__ edge, int E,
                                              const float* __restrict__ att,
                                              int* __restrict__ cursor,
                                              int* __restrict__ ovf_cnt,
                                              float2* __restrict__ pse,
                                              float4* __restrict__ ovf) {
    __shared__ int s_or;
    int t = threadIdx.x;
    if (t == 0) s_or = 0;
    __syncthreads();
    int nw = 2 * E < 512 ? 2 * E : 512;
    int iw = t * 2 + 1;
    int vw = (iw < nw) ? edge[iw] : 0;
    if (vw != 0) atomicOr(&s_or, 1);
    __syncthreads();
    int sh = (s_or == 0) ? 1 : 0;  // 1 => int64 stride, 0 => int32

    int e = blockIdx.x * 256 + t;
    if (e < E) {
        int s = edge[(size_t)e << sh];
        int d = edge[(size_t)(E + e) << sh];
        int slot = atomicAdd(&cursor[d], 1);
        float a = att[e];
        if (slot < CAP) {
            pse[(size_t)d * CAP + slot] = make_float2(__int_as_float(s), a);
        } else {
            int oi = atomicAdd(ovf_cnt, 1);
            ovf[oi] = make_float4(__int_as_float(d), __int_as_float(s), a, 0.f);
        }
    }
}

// One WAVE per node, 2 nodes per 128-thread block. Lane covers 4 cols (8B);
// half-wave 0 takes even edges, half-wave 1 odd edges -> one dwordx2 instr
// gathers two full 256B src rows. x4 unroll = 8 rows in flight.
// Final cross-half combine via __shfl_xor(.,32).
__global__ __launch_bounds__(128) void k_agg(const unsigned short* __restrict__ x,
                                             const float2* __restrict__ pse,
                                             const int* __restrict__ cursor,
                                             const int* __restrict__ ovf_cnt,
                                             const float4* __restrict__ ovf,
                                             unsigned short* __restrict__ agg, int N) {
    int wave = threadIdx.x >> 6;
    int lane = threadIdx.x & 63;
    int half = lane >> 5;        // which edge of a pair
    int l32 = lane & 31;         // col group: cols 4*l32 .. 4*l32+3
    int n = blockIdx.x * 2 + wave;
    bool valid = n < N;
    int deg = valid ? cursor[n] : 0;
    int m = min(deg, CAP);

    __shared__ float2 sp[2][CAP];
    if (lane < m) sp[wave][lane] = pse[(size_t)n * CAP + lane];
    __syncthreads();

    const unsigned short* xb = x + 4 * l32;
    float s0 = 0.f, s1 = 0.f, s2 = 0.f, s3 = 0.f;

#define ACC(u, a)                                                   \
    do {                                                            \
        s0 = fmaf(bf2f((unsigned short)((u).x & 0xffff)), (a), s0); \
        s1 = fmaf(bf2f((unsigned short)((u).x >> 16)), (a), s1);    \
        s2 = fmaf(bf2f((unsigned short)((u).y & 0xffff)), (a), s2); \
        s3 = fmaf(bf2f((unsigned short)((u).y >> 16)), (a), s3);    \
    } while (0)

    int j = 0;
    for (; j + 8 <= m; j += 8) {
        float2 pA = sp[wave][j + 0 + half];
        float2 pB = sp[wave][j + 2 + half];
        float2 pC = sp[wave][j + 4 + half];
        float2 pD = sp[wave][j + 6 + half];
        uint2 uA = *(const uint2*)(xb + (size_t)__float_as_int(pA.x) * HDIM);
        uint2 uB = *(const uint2*)(xb + (size_t)__float_as_int(pB.x) * HDIM);
        uint2 uC = *(const uint2*)(xb + (size_t)__float_as_int(pC.x) * HDIM);
        uint2 uD = *(const uint2*)(xb + (size_t)__float_as_int(pD.x) * HDIM);
        ACC(uA, pA.y);
        ACC(uB, pB.y);
        ACC(uC, pC.y);
        ACC(uD, pD.y);
    }
    for (; j + 2 <= m; j += 2) {
        float2 p = sp[wave][j + half];
        uint2 u = *(const uint2*)(xb + (size_t)__float_as_int(p.x) * HDIM);
        ACC(u, p.y);
    }
    if (j < m && half == 0) {   // single leftover edge
        float2 p = sp[wave][j];
        uint2 u = *(const uint2*)(xb + (size_t)__float_as_int(p.x) * HDIM);
        ACC(u, p.y);
    }

    // Overflow correctness path (normally ovf_cnt == 0 -> skipped).
    int oc = ovf_cnt[0];
    if (oc > 0 && valid) {
        for (int k = half; k < oc; k += 2) {
            float4 f = ovf[k];
            if (__float_as_int(f.x) == n) {
                uint2 u = *(const uint2*)(xb + (size_t)__float_as_int(f.y) * HDIM);
                ACC(u, f.z);
            }
        }
    }
#undef ACC

    s0 += __shfl_xor(s0, 32);
    s1 += __shfl_xor(s1, 32);
    s2 += __shfl_xor(s2, 32);
    s3 += __shfl_xor(s3, 32);

    if (valid && half == 0) {
        float md = fmaxf((float)deg, 1.0f);
        ushort4 o;
        o.x = f2bf(s0 / md);
        o.y = f2bf(s1 / md);
        o.z = f2bf(s2 / md);
        o.w = f2bf(s3 / md);
        *(ushort4*)(agg + (size_t)n * HDIM + 4 * l32) = o;
    }
}

// out[M,128] = relu( [X | AGG][M,256]bf16 @ W[256,128] + b ), MFMA 16x16x32.
// R10: Wt staged in LDS (64KB, XOR-swizzled quads: <=4-way bank conflicts),
// A-frags preloaded to registers. B-frag reads become ds_read_b128.
// C/D: col=lane&15, row=quad*4+reg. Block = 4 waves, 64 rows/block.
__global__ __launch_bounds__(256) void k_gemm_mfma(const unsigned short* __restrict__ X,
                                                   const unsigned short* __restrict__ AGG,
                                                   const unsigned short* __restrict__ Wt,
                                                   const float* __restrict__ bias,
                                                   float* __restrict__ outF,
                                                   unsigned short* __restrict__ outB,
                                                   int M) {
    __shared__ __align__(16) unsigned short sW[128 * 256];   // 64 KB

    int tid = threadIdx.x;
    int wave = tid >> 6;
    int lane = tid & 63;
    int l16 = lane & 15;
    int quad = lane >> 4;

    // ---- Stage Wt -> LDS, swizzled: quad' = quad ^ (row & 3) ----
#pragma unroll
    for (int it = 0; it < 16; ++it) {
        int chunk = it * 256 + tid;      // 16B chunks, 0..4095
        int row = chunk >> 5;            // 0..127
        int c5 = chunk & 31;             // 32 chunks per row
        int kc = c5 >> 2;
        int q = c5 & 3;
        int qs = q ^ (row & 3);
        uint4 v = *(const uint4*)(Wt + (size_t)chunk * 8);
        *(uint4*)(sW + row * 256 + kc * 32 + qs * 8) = v;
    }

    // ---- Preload A-frags (8 x 16B) while staging is in flight ----
    int row = blockIdx.x * 64 + wave * 16 + l16;
    int rowA = min(row, M - 1);
    const unsigned short* xrow = X + (size_t)rowA * HDIM + quad * 8;
    const unsigned short* arow = AGG + (size_t)rowA * HDIM + quad * 8;
    bf16x8 af[8];
#pragma unroll
    for (int kc = 0; kc < 4; ++kc) af[kc] = *(const bf16x8*)(xrow + kc * 32);
#pragma unroll
    for (int kc = 4; kc < 8; ++kc) af[kc] = *(const bf16x8*)(arow + (kc - 4) * 32);

    __syncthreads();

    floatx4 acc[8];
#pragma unroll
    for (int c = 0; c < 8; ++c) acc[c] = (floatx4){0.f, 0.f, 0.f, 0.f};

#pragma unroll
    for (int kc = 0; kc < 8; ++kc) {
#pragma unroll
        for (int c = 0; c < 8; ++c) {
            int rb = c * 16 + l16;
            int qs = quad ^ (rb & 3);
            bf16x8 bfr = *(const bf16x8*)(sW + rb * 256 + kc * 32 + qs * 8);
            acc[c] = __builtin_amdgcn_mfma_f32_16x16x32_bf16(af[kc], bfr, acc[c], 0, 0, 0);
        }
    }

    int orow0 = blockIdx.x * 64 + wave * 16 + quad * 4;
#pragma unroll
    for (int c = 0; c < 8; ++c) {
        int col = c * 16 + l16;
        float bv = bias[col];
#pragma unroll
        for (int r = 0; r < 4; ++r) {
            int orow = orow0 + r;
            if (orow < M) {
                float v = fmaxf(acc[c][r] + bv, 0.f);
                if (outF) outF[(size_t)orow * 128 + col] = v;
                else outB[(size_t)orow * 128 + col] = f2bf(v);
            }
        }
    }
}

extern "C" void kernel_launch(void* const* d_in, const int* in_sizes, int n_in,
                              void* d_out, int out_size, void* d_ws, size_t ws_size,
                              hipStream_t stream) {
    const float* data = (const float*)d_in[0];
    const int* edge = (const int*)d_in[1];
    const float* att = (const float*)d_in[2];
    const float* w1 = (const float*)d_in[3];
    const float* b1 = (const float*)d_in[4];
    const float* w2 = (const float*)d_in[5];
    const float* b2 = (const float*)d_in[6];

    const int N = in_sizes[0] / HDIM;
    const int E = in_sizes[1] / 2;

    char* ws = (char*)d_ws;
    size_t o = 0;
    auto carve = [&](size_t bytes) -> char* {
        char* r = ws + o;
        o = (o + bytes + 255) & ~(size_t)255;
        return r;
    };
    int* cursor = (int*)carve((size_t)(N + 4) * 4);   // cursor[N] + ovf_cnt at [N]
    int* ovf_cnt = cursor + N;
    float2* pse = (float2*)carve((size_t)N * CAP * 8);        // padded CSR {src, att}
    float4* ovf = (float4*)carve((size_t)E * 16);             // overflow (usually empty)
    unsigned short* data_bf = (unsigned short*)carve((size_t)N * 128 * 2);
    unsigned short* w1t = (unsigned short*)carve(256 * 128 * 2);
    unsigned short* w2t = (unsigned short*)carve(256 * 128 * 2);
    unsigned short* agg_bf = (unsigned short*)carve((size_t)N * 128 * 2);
    unsigned short* out1_bf = (unsigned short*)carve((size_t)N * 128 * 2);
    float* outF = (float*)d_out;

    int nz = N + 4;
    int zb = (nz + 255) / 256;
    int n4 = N * 128 / 4;
    int cb = (n4 + 255) / 256;
    k_setup<<<zb + cb + 256, 256, 0, stream>>>(cursor, nz, data, data_bf, n4,
                                               w1, w1t, w2, w2t, zb, cb);

    k_fill<<<(E + 255) / 256, 256, 0, stream>>>(edge, E, att, cursor, ovf_cnt, pse, ovf);

    int ga = (N + 1) / 2;
    int gb = (N + 63) / 64;
    // Layer 1
    k_agg<<<ga, 128, 0, stream>>>(data_bf, pse, cursor, ovf_cnt, ovf, agg_bf, N);
    k_gemm_mfma<<<gb, 256, 0, stream>>>(data_bf, agg_bf, w1t, b1, nullptr, out1_bf, N);
    // Layer 2
    k_agg<<<ga, 128, 0, stream>>>(out1_bf, pse, cursor, ovf_cnt, ovf, agg_bf, N);
    k_gemm_mfma<<<gb, 256, 0, stream>>>(out1_bf, agg_bf, w2t, b2, outF, nullptr, N);
}